// Round 11
// baseline (167.923 us; speedup 1.0000x reference)
//
#include <hip/hip_runtime.h>
#include <stdint.h>

#define BATCH 32
#define H 512
#define W 512
#define NACC 16
#define TH 32              // center rows per tile
#define HALO 9             // coverage steps a=1..9
#define RH (TH + 2*HALO)   // 50 rows incl. halo
#define NWORDS (RH*8)      // 400 mask words per image
#define NT 1024
#define NW (NT/64)         // 16 waves
#define NTILE (H/TH)       // 16
#define NBLK (NTILE*BATCH) // 512 blocks = 2/CU

// part[fid*NACC + k] per-block partials (no atomics, deterministic):
//  0: sum(p*g)  1: sum(p)  2: sum(g)
//  3: cnt_pe 4: cnt_pm 5: cnt_pj  6: cnt_ge 7: cnt_gm 8: cnt_gj
//  9: int_e 10: int_m 11: int_j
// 12: dsum_p2g 13: cnt_p2g 14: dsum_g2p 15: cnt_g2p

__global__ __launch_bounds__(NT, 4) void fused_kernel(
    const float* __restrict__ pred, const float* __restrict__ gt,
    float* __restrict__ part)
{
    // single-buffered masks (+1 pad word each end for clamped neighbor reads)
    __shared__ uint64_t MpS[NWORDS + 2];
    __shared__ uint64_t MgS[NWORDS + 2];
    __shared__ float    red[NW][16];

    uint64_t* Mp = MpS + 1;   // flat index o = row*8 + word
    uint64_t* Mg = MgS + 1;

    // fid = tile*32 + b: vertically-adjacent tiles of one image are 32 apart
    // => same XCD under mod-8 round-robin dispatch (halo rows share L2).
    int fid  = blockIdx.x;
    int b    = fid & 31;
    int tile = fid >> 5;

    const float* pimg = pred + (size_t)b * H * W;
    const float* gimg = gt   + (size_t)b * H * W;
    int y0 = tile * TH;
    int tid = threadIdx.x, lane = tid & 63, wid = tid >> 6;

    // ---- Phase A1: ballot masks + dice sums, rows y0-9..y0+40 (400 tasks,
    // x2 unroll: 4 loads in flight/wave-iter)
    float v0 = 0.f, v1 = 0.f;
    for (int s = wid; s < NWORDS; s += 2 * NW) {
        int sB = s + NW;
        bool okB = sB < NWORDS;              // wave-uniform
        int rA = s >> 3, rB = sB >> 3;
        int ryA = y0 - HALO + rA, ryB = y0 - HALO + rB;
        float vpA = 0.f, vgA = 0.f, vpB = 0.f, vgB = 0.f;
        if ((unsigned)ryA < (unsigned)H) {
            int i0 = ryA * W + (s & 7) * 64 + lane;
            vpA = pimg[i0]; vgA = gimg[i0];
        }
        if (okB && (unsigned)ryB < (unsigned)H) {
            int i1 = ryB * W + (sB & 7) * 64 + lane;
            vpB = pimg[i1]; vgB = gimg[i1];
        }
        unsigned long long mpA = __ballot(vpA > 0.5f);
        unsigned long long mgA = __ballot(vgA > 0.5f);
        if (lane == 0) { Mp[s] = mpA; Mg[s] = mgA; }
        if (rA >= HALO && rA < HALO + TH) { v1 += vpA; v0 += (vgA > 0.5f) ? vpA : 0.f; }
        if (okB) {
            unsigned long long mpB = __ballot(vpB > 0.5f);
            unsigned long long mgB = __ballot(vgB > 0.5f);
            if (lane == 0) { Mp[sB] = mpB; Mg[sB] = mgB; }
            if (rB >= HALO && rB < HALO + TH) { v1 += vpB; v0 += (vgB > 0.5f) ? vpB : 0.f; }
        }
    }
    if (tid == 0) { MpS[0] = 0; MpS[NWORDS + 1] = 0; MgS[0] = 0; MgS[NWORDS + 1] = 0; }

    // ---- Phase A2 (still PRE-barrier, no LDS): pred-side float stencil.
    // Wave-edge colsums via exec-masked direct loads (no LDS EC array).
    // pe/pm/pj flags packed 3 bits/pixel into ppack (16 px/thread).
    uint64_t ppack = 0ULL;
    {
        int qi = tid & 127, h = tid >> 7;     // 128 quads x 8 row-groups of 4
        int x4 = qi * 4;
        int ys = y0 + h * 4;
        bool needL = (lane == 0)  && (qi == 64);   // left neighbor col 255
        bool needR = (lane == 63) && (qi == 63);   // right neighbor col 256
        bool needE = needL || needR;
        int ecol = needL ? 255 : 256;
        float em = 0.f, ec = 0.f;
        if (needE) {
            if (ys > 0) em = pimg[(size_t)(ys - 1) * W + ecol];
            ec = pimg[(size_t)ys * W + ecol];
        }
        float4 pm4 = (ys > 0) ? *(const float4*)(pimg + (size_t)(ys - 1) * W + x4)
                              : make_float4(0, 0, 0, 0);
        float4 pc4 = *(const float4*)(pimg + (size_t)ys * W + x4);
        #pragma unroll
        for (int r = 0; r < 4; ++r) {
            int y = ys + r;
            float4 pp4 = (y < H - 1) ? *(const float4*)(pimg + (size_t)(y + 1) * W + x4)
                                     : make_float4(0, 0, 0, 0);
            float ep = 0.f;
            if (needE && y < H - 1) ep = pimg[(size_t)(y + 1) * W + ecol];
            float ecs = em + ec + ep;

            float ps[6];
            ps[1] = pm4.x + pc4.x + pp4.x; ps[2] = pm4.y + pc4.y + pp4.y;
            ps[3] = pm4.z + pc4.z + pp4.z; ps[4] = pm4.w + pc4.w + pp4.w;
            float psl = __shfl_up(ps[4], 1, 64);
            float psr = __shfl_down(ps[1], 1, 64);
            if (lane == 0)  psl = needL ? ecs : 0.f;   // qi==0 -> border 0
            if (lane == 63) psr = needR ? ecs : 0.f;   // qi==127 -> border 0
            ps[0] = psl; ps[5] = psr;

            float pcv[4] = {pc4.x, pc4.y, pc4.z, pc4.w};
            #pragma unroll
            for (int j = 0; j < 4; ++j) {
                float np = ps[j] + ps[j + 1] + ps[j + 2] - pcv[j];
                bool pon = pcv[j] > 0.5f;
                uint32_t f = (uint32_t)(pon && (np == 1.f))
                           | ((uint32_t)(pon && (np == 2.f)) << 1)
                           | ((uint32_t)(pon && (np > 2.f))  << 2);
                ppack |= (uint64_t)f << (3 * (r * 4 + j));
            }
            pm4 = pc4; pc4 = pp4; em = ec; ec = ep;
        }
    }
    __syncthreads();   // drains ballot LDS writes AND all pre-issued loads

    // ---- Phase B: gt-side classification from Mg bit windows (post-barrier)
    uint64_t gpack = 0ULL;
    {
        int qi = tid & 127, h = tid >> 7;
        int wdx = qi >> 4;                    // gt word for this quad
        int ss = (qi & 15) * 4;               // bit offset of x4 in word
        auto win6 = [&](int rb) -> uint32_t {
            const uint64_t* row = &Mg[rb * 8];
            uint64_t bm = row[wdx];
            if (ss == 0) {
                uint64_t lo = wdx ? row[wdx - 1] : 0ULL;
                return (uint32_t)(((bm << 1) | (lo >> 63)) & 0x3FULL);
            }
            uint32_t v = (uint32_t)((bm >> (ss - 1)) & 0x3FULL);
            if (ss == 60) {
                uint64_t hi = (wdx < 7) ? row[wdx + 1] : 0ULL;
                v |= ((uint32_t)hi & 1u) << 5;
            }
            return v;
        };
        int rb0 = h * 4 + HALO - 1;           // bit-row of (ys-1)
        uint32_t wU = win6(rb0), wM = win6(rb0 + 1);
        #pragma unroll
        for (int r = 0; r < 4; ++r) {
            uint32_t wD = win6(rb0 + 2 + r);
            #pragma unroll
            for (int j = 0; j < 4; ++j) {
                uint32_t n9 = ((wU >> j) & 7u) | (((wM >> j) & 7u) << 3) | (((wD >> j) & 7u) << 6);
                uint32_t cen = (wM >> (j + 1)) & 1u;
                int ng = __popc(n9) - (int)cen;
                uint32_t f = cen ? ((uint32_t)(ng == 1)
                                 | ((uint32_t)(ng == 2) << 1)
                                 | ((uint32_t)(ng > 2)  << 2)) : 0u;
                gpack |= (uint64_t)f << (3 * (r * 4 + j));
            }
            wU = wM; wM = wD;
        }
    }
    const uint64_t M0 = 0x249249249249ULL;    // bit 3k   (e)
    const uint64_t M1 = 0x492492492492ULL;    // bit 3k+1 (m)
    const uint64_t M2 = 0x924924924924ULL;    // bit 3k+2 (j)
    uint64_t ipack = ppack & gpack;

    // ---- Phase C: barrier-free register distance (waves 0-7 only).
    // C_a = S_a(V_a); incremental C_a = C_{a-1} | S_{a-1}(N_a) | shift_a(V_a).
    int dsum_p = 0, dcnt_p = 0, dsum_g = 0, dcnt_g = 0;
    if (tid < 512) {
        bool isP = tid < 256;                  // waves 0-3: p2g; 4-7: g2p
        int idx = tid & 255;
        int o   = (HALO + (idx >> 3)) * 8 + (idx & 7);  // rc in [9,40]
        int w   = idx & 7;
        bool wL = (w > 0), wR = (w < 7);
        const uint64_t* MT = isP ? Mp : Mg;
        const uint64_t* MV = isP ? Mg : Mp;

        uint64_t T = MT[o];
        int dcnt = __popcll(T);
        int dsum = dcnt;                       // a=0 baseline (dist >= 1)
        uint64_t VM = MV[o];
        uint64_t VL = wL ? MV[o - 1] : 0ULL;
        uint64_t VR = wR ? MV[o + 1] : 0ULL;
        uint64_t C = VM;

        #pragma unroll
        for (int a = 1; a <= 9; ++a) {
            int lo = o - 8 * a, hi = o + 8 * a;
            uint64_t NM = MV[lo] | MV[hi];
            uint64_t NL = wL ? (MV[lo - 1] | MV[hi - 1]) : 0ULL;
            uint64_t NR = wR ? (MV[lo + 1] | MV[hi + 1]) : 0ULL;
            uint64_t SL = NL, SM = NM, SR = NR;
            const int m = a - 1;
            if (m >= 1) {
                SM |= (SM << 1) | (SM >> 1) | (SL >> 63) | (SR << 63);
                SL |= SL << 1; SR |= SR >> 1;
            }
            if (m >= 2) {
                const int s = (m == 2) ? 1 : 2;
                SM |= (SM << s) | (SM >> s) | (SL >> (64 - s)) | (SR << (64 - s));
                SL |= SL << s; SR |= SR >> s;
            }
            if (m >= 4) {
                const int s = (m - 3 < 4) ? (m - 3) : 4;
                SM |= (SM << s) | (SM >> s) | (SL >> (64 - s)) | (SR << (64 - s));
                SL |= SL << s; SR |= SR >> s;
            }
            if (m >= 8) {
                const int s = m - 7;
                SM |= (SM << s) | (SM >> s) | (SL >> (64 - s)) | (SR << (64 - s));
                SL |= SL << s; SR |= SR >> s;
            }
            C |= SM;
            VL |= NL; VM |= NM; VR |= NR;
            C |= (VM << a) | (VM >> a) | (VL >> (64 - a)) | (VR << (64 - a));
            dsum += __popcll(T & ~C);
        }
        if (isP) { dsum_p = dsum; dcnt_p = dcnt; }
        else     { dsum_g = dsum; dcnt_g = dcnt; }
    }

    // ---- Reductions -> per-block partials (no atomics)
    float vals[16];
    vals[0]  = v0; vals[1] = v1;
    vals[2]  = (float)dcnt_g;                 // sum(g) = popc of gt targets
    vals[3]  = (float)__popcll(ppack & M0);
    vals[4]  = (float)__popcll(ppack & M1);
    vals[5]  = (float)__popcll(ppack & M2);
    vals[6]  = (float)__popcll(gpack & M0);
    vals[7]  = (float)__popcll(gpack & M1);
    vals[8]  = (float)__popcll(gpack & M2);
    vals[9]  = (float)__popcll(ipack & M0);
    vals[10] = (float)__popcll(ipack & M1);
    vals[11] = (float)__popcll(ipack & M2);
    vals[12] = (float)dsum_p; vals[13] = (float)dcnt_p;
    vals[14] = (float)dsum_g; vals[15] = (float)dcnt_g;
    #pragma unroll
    for (int j = 0; j < 16; ++j)
        #pragma unroll
        for (int off = 32; off; off >>= 1)
            vals[j] += __shfl_down(vals[j], off, 64);
    if (lane == 0) {
        #pragma unroll
        for (int j = 0; j < 16; ++j) red[wid][j] = vals[j];
    }
    __syncthreads();
    if (tid < 16) {
        float s = 0.f;
        #pragma unroll
        for (int wv = 0; wv < NW; ++wv) s += red[wv][tid];
        part[fid * NACC + tid] = s;
    }
}

// ---------------------------------------------------------------------------
// Final: reduce 512x16 partials -> 32x16 -> scalar. One block, deterministic.
// ---------------------------------------------------------------------------
__global__ __launch_bounds__(512) void final_kernel(
    const float* __restrict__ part, float* __restrict__ out)
{
    __shared__ float sacc[BATCH][NACC];
    __shared__ float tri[BATCH][3];
    int t = threadIdx.x;
    {
        int b = t >> 4, k = t & 15;
        float s = 0.f;
        #pragma unroll 4
        for (int j = 0; j < NTILE; ++j)            // fid = j*32 + b
            s += part[((j << 5) + b) * NACC + k];
        sacc[b][k] = s;
    }
    __syncthreads();
    if (t < BATCH) {
        const float* a = sacc[t];
        float inter = a[0], psum = a[1], gsum = a[2];
        float dice = (2.f * inter + 1.f) / (psum + gsum + 1.f);

        float pe = a[3], pm = a[4], pj = a[5];
        float ge = a[6], gm = a[7], gj = a[8];
        float ie = a[9], im = a[10], ij = a[11];
        float e_iou = (ie + 1.f) / (pe + ge - ie + 1.f);
        float m_iou = (im + 1.f) / (pm + gm - im + 1.f);
        float j_iou = (ij + 1.f) / (pj + gj - ij + 1.f);
        float total = ge + gj + gm + 1.f;
        float sloss = 1.f - ((ge / total) * e_iou + (gj / total) * j_iou + (gm / total) * m_iou);

        float p2g = a[12] / (a[13] + 1.f);
        float g2p = a[14] / (a[15] + 1.f);
        float med = ((p2g + g2p) * 0.5f) / 10.f;
        tri[t][0] = dice; tri[t][1] = sloss; tri[t][2] = med;
    }
    __syncthreads();
    if (t == 0) {
        float dice = 0.f, sloss = 0.f, med = 0.f;
        for (int b = 0; b < BATCH; ++b) {
            dice += tri[b][0]; sloss += tri[b][1]; med += tri[b][2];
        }
        float dice_loss  = 1.f - dice / (float)BATCH;
        float structural = sloss / (float)BATCH;
        float medial     = med / (float)BATCH;
        float avg = (dice_loss + structural + medial) / 3.f;
        float r = dice_loss  / (dice_loss  + 1.f) * avg
                + structural / (structural + 1.f) * avg
                + medial     / (medial     + 1.f) * avg;
        out[0] = r;
    }
}

extern "C" void kernel_launch(void* const* d_in, const int* in_sizes, int n_in,
                              void* d_out, int out_size, void* d_ws, size_t ws_size,
                              hipStream_t stream)
{
    const float* pred = (const float*)d_in[0];
    const float* gt   = (const float*)d_in[1];
    float* part = (float*)d_ws;
    float* out  = (float*)d_out;

    fused_kernel<<<dim3(NBLK), NT, 0, stream>>>(pred, gt, part);
    final_kernel<<<1, 512, 0, stream>>>(part, out);
}

// Round 12
// 125.515 us; speedup vs baseline: 1.3379x; 1.3379x over previous
//
#include <hip/hip_runtime.h>
#include <stdint.h>

#define BATCH 32
#define H 512
#define W 512
#define NACC 16
#define TH 32              // center rows per tile
#define HALO 9             // coverage steps a=1..9
#define RH (TH + 2*HALO)   // 50 rows incl. halo
#define NWORDS (RH*8)      // 400 mask words per image
#define NT 1024
#define NW (NT/64)         // 16 waves
#define NTILE (H/TH)       // 16
#define NBLK (NTILE*BATCH) // 512 blocks = 2/CU

// part[fid*NACC + k] per-block partials (no atomics, deterministic):
//  0: sum(p*g)  1: sum(p)  2: sum(g)
//  3: cnt_pe 4: cnt_pm 5: cnt_pj  6: cnt_ge 7: cnt_gm 8: cnt_gj
//  9: int_e 10: int_m 11: int_j
// 12: dsum_p2g 13: cnt_p2g 14: dsum_g2p 15: cnt_g2p

__global__ __launch_bounds__(NT, 4) void fused_kernel(
    const float* __restrict__ pred, const float* __restrict__ gt,
    float* __restrict__ part)
{
    // single-buffered masks (+1 pad word each end)
    __shared__ uint64_t MpS[NWORDS + 2];
    __shared__ uint64_t MgS[NWORDS + 2];
    __shared__ float    EC[2][TH];       // pred colsums at cols 255|256
    __shared__ float    red[NW][16];

    uint64_t* Mp = MpS + 1;   // flat index o = row*8 + word
    uint64_t* Mg = MgS + 1;

    // fid = tile*32 + b: vertically-adjacent tiles of one image are 32 apart
    // => same XCD under mod-8 round-robin dispatch (halo rows share L2).
    int fid  = blockIdx.x;
    int b    = fid & 31;
    int tile = fid >> 5;

    const float* pimg = pred + (size_t)b * H * W;
    const float* gimg = gt   + (size_t)b * H * W;
    int y0 = tile * TH;
    int tid = threadIdx.x, lane = tid & 63, wid = tid >> 6;

    // ---- Phase 1: ballot masks + dice sums, rows y0-9..y0+40 (400 tasks,
    // x2 unroll: 4 loads in flight/wave-iter)
    float v0 = 0.f, v1 = 0.f;
    for (int s = wid; s < NWORDS; s += 2 * NW) {
        int sB = s + NW;                          // always < 400 (400=25*16)
        int rA = s >> 3, rB = sB >> 3;
        int ryA = y0 - HALO + rA, ryB = y0 - HALO + rB;
        float vpA = 0.f, vgA = 0.f, vpB = 0.f, vgB = 0.f;
        if ((unsigned)ryA < (unsigned)H) {
            int i0 = ryA * W + (s & 7) * 64 + lane;
            vpA = pimg[i0]; vgA = gimg[i0];
        }
        if ((unsigned)ryB < (unsigned)H) {
            int i1 = ryB * W + (sB & 7) * 64 + lane;
            vpB = pimg[i1]; vgB = gimg[i1];
        }
        unsigned long long mpA = __ballot(vpA > 0.5f);
        unsigned long long mgA = __ballot(vgA > 0.5f);
        unsigned long long mpB = __ballot(vpB > 0.5f);
        unsigned long long mgB = __ballot(vgB > 0.5f);
        if (lane == 0) {
            Mp[s]  = mpA; Mg[s]  = mgA;
            Mp[sB] = mpB; Mg[sB] = mgB;
        }
        if (rA >= HALO && rA < HALO + TH) { v1 += vpA; v0 += (vgA > 0.5f) ? vpA : 0.f; }
        if (rB >= HALO && rB < HALO + TH) { v1 += vpB; v0 += (vgB > 0.5f) ? vpB : 0.f; }
    }
    if (tid == 0) { MpS[0] = 0; MpS[NWORDS + 1] = 0; MgS[0] = 0; MgS[NWORDS + 1] = 0; }
    // pred edge colsums (cols 255,256) for the cross-wave stencil halo
    if (tid < 2 * TH) {
        int c = tid >> 5, r = tid & (TH - 1);
        int y = y0 + r, col = 255 + c;
        float sum = (y > 0     ? pimg[(size_t)(y - 1) * W + col] : 0.f)
                  +              pimg[(size_t)y * W + col]
                  + (y < H - 1 ? pimg[(size_t)(y + 1) * W + col] : 0.f);
        EC[c][r] = sum;
    }
    __syncthreads();

    // ---- Stencil: pred via floats (rolling rows), gt via bit popcounts.
    // 9 classification counters packed into one u64 (7-bit fields, max 16/thr)
    uint64_t cpack = 0ULL;
    {
        int qi = tid & 127, h = tid >> 7;     // h in 0..7, 4 rows each
        int x4 = qi * 4;
        int wdx = qi >> 4;                    // gt word for this quad
        int ss = (qi & 15) * 4;               // bit offset of x4 in word

        auto win6 = [&](int rb) -> uint32_t {
            const uint64_t* row = &Mg[rb * 8];
            uint64_t bm = row[wdx];
            if (ss == 0) {
                uint64_t lo = wdx ? row[wdx - 1] : 0ULL;
                return (uint32_t)(((bm << 1) | (lo >> 63)) & 0x3FULL);
            }
            uint32_t v = (uint32_t)((bm >> (ss - 1)) & 0x3FULL);
            if (ss == 60) {
                uint64_t hi = (wdx < 7) ? row[wdx + 1] : 0ULL;
                v |= ((uint32_t)hi & 1u) << 5;
            }
            return v;
        };

        int ys = y0 + h * 4;
        int rb0 = h * 4 + HALO - 1;           // bit-row of (ys-1)
        uint32_t wU = win6(rb0), wM = win6(rb0 + 1);

        float4 pm4, pc4;
        {
            bool hm = ys > 0;
            pm4 = hm ? *(const float4*)(pimg + (size_t)(ys - 1) * W + x4)
                     : make_float4(0, 0, 0, 0);
            pc4 = *(const float4*)(pimg + (size_t)ys * W + x4);
        }
        for (int r = 0; r < 4; ++r) {
            int y = ys + r;
            float4 pp4 = (y < H - 1) ? *(const float4*)(pimg + (size_t)(y + 1) * W + x4)
                                     : make_float4(0, 0, 0, 0);
            uint32_t wD = win6(rb0 + 2 + r);
            int ry = h * 4 + r;

            float ps[6];
            ps[1] = pm4.x + pc4.x + pp4.x; ps[2] = pm4.y + pc4.y + pp4.y;
            ps[3] = pm4.z + pc4.z + pp4.z; ps[4] = pm4.w + pc4.w + pp4.w;
            float psl = __shfl_up(ps[4], 1, 64);
            float psr = __shfl_down(ps[1], 1, 64);
            if (lane == 0)  psl = (qi == 0)   ? 0.f : EC[0][ry];
            if (lane == 63) psr = (qi == 127) ? 0.f : EC[1][ry];
            ps[0] = psl; ps[5] = psr;

            float pcv[4] = {pc4.x, pc4.y, pc4.z, pc4.w};
            #pragma unroll
            for (int j = 0; j < 4; ++j) {
                float np = ps[j] + ps[j + 1] + ps[j + 2] - pcv[j];
                bool pon = pcv[j] > 0.5f;
                bool pe  = pon && (np == 1.f);
                bool pmb = pon && (np == 2.f);
                bool pjb = pon && (np > 2.f);
                uint32_t n9 = ((wU >> j) & 7u) | (((wM >> j) & 7u) << 3) | (((wD >> j) & 7u) << 6);
                uint32_t cen = (wM >> (j + 1)) & 1u;
                int ng = __popc(n9) - (int)cen;
                bool gon = cen != 0u;
                bool ge  = gon && (ng == 1);
                bool gmb = gon && (ng == 2);
                bool gjb = gon && (ng > 2);
                cpack += (uint64_t)pe
                       | ((uint64_t)pmb << 7)
                       | ((uint64_t)pjb << 14)
                       | ((uint64_t)ge  << 21)
                       | ((uint64_t)gmb << 28)
                       | ((uint64_t)gjb << 35)
                       | ((uint64_t)(pe  && ge)  << 42)
                       | ((uint64_t)(pmb && gmb) << 49)
                       | ((uint64_t)(pjb && gjb) << 56);
            }
            pm4 = pc4; pc4 = pp4; wU = wM; wM = wD;
        }
    }

    // ---- Distance: barrier-free register dilation (waves 0-7 active).
    // C_a = S_a(V_a); incremental C_a = C_{a-1} | S_{a-1}(N_a) | shift_a(V_a).
    // S = symmetric horizontal range-OR via exact shift-doubling w/ carries.
    int dsum_p = 0, dcnt_p = 0, dsum_g = 0, dcnt_g = 0;
    if (tid < 512) {
        bool isP = tid < 256;                  // waves 0-3: p2g; 4-7: g2p
        int idx = tid & 255;
        int o   = (HALO + (idx >> 3)) * 8 + (idx & 7);  // rc in [9,40]
        int w   = idx & 7;
        bool wL = (w > 0), wR = (w < 7);
        const uint64_t* MT = isP ? Mp : Mg;
        const uint64_t* MV = isP ? Mg : Mp;

        uint64_t T = MT[o];
        int dcnt = __popcll(T);
        int dsum = dcnt;                       // a=0 baseline (dist >= 1)
        uint64_t VM = MV[o];
        uint64_t VL = wL ? MV[o - 1] : 0ULL;
        uint64_t VR = wR ? MV[o + 1] : 0ULL;
        uint64_t C = VM;

        #pragma unroll
        for (int a = 1; a <= 9; ++a) {
            int lo = o - 8 * a, hi = o + 8 * a;
            uint64_t NM = MV[lo] | MV[hi];
            uint64_t NL = wL ? (MV[lo - 1] | MV[hi - 1]) : 0ULL;
            uint64_t NR = wR ? (MV[lo + 1] | MV[hi + 1]) : 0ULL;
            uint64_t SL = NL, SM = NM, SR = NR;
            const int m = a - 1;
            if (m >= 1) {
                SM |= (SM << 1) | (SM >> 1) | (SL >> 63) | (SR << 63);
                SL |= SL << 1; SR |= SR >> 1;
            }
            if (m >= 2) {
                const int s = (m == 2) ? 1 : 2;
                SM |= (SM << s) | (SM >> s) | (SL >> (64 - s)) | (SR << (64 - s));
                SL |= SL << s; SR |= SR >> s;
            }
            if (m >= 4) {
                const int s = (m - 3 < 4) ? (m - 3) : 4;
                SM |= (SM << s) | (SM >> s) | (SL >> (64 - s)) | (SR << (64 - s));
                SL |= SL << s; SR |= SR >> s;
            }
            if (m >= 8) {
                const int s = m - 7;
                SM |= (SM << s) | (SM >> s) | (SL >> (64 - s)) | (SR << (64 - s));
                SL |= SL << s; SR |= SR >> s;
            }
            C |= SM;
            VL |= NL; VM |= NM; VR |= NR;
            C |= (VM << a) | (VM >> a) | (VL >> (64 - a)) | (VR << (64 - a));
            dsum += __popcll(T & ~C);
        }
        if (isP) { dsum_p = dsum; dcnt_p = dcnt; }
        else     { dsum_g = dsum; dcnt_g = dcnt; }
    }

    // ---- Reductions -> per-block partials (no atomics)
    float vals[16];
    vals[0] = v0; vals[1] = v1;
    vals[2]  = (float)dcnt_g;                 // sum(g) = popc of gt targets
    vals[3]  = (float)((cpack      ) & 0x7F);
    vals[4]  = (float)((cpack >> 7 ) & 0x7F);
    vals[5]  = (float)((cpack >> 14) & 0x7F);
    vals[6]  = (float)((cpack >> 21) & 0x7F);
    vals[7]  = (float)((cpack >> 28) & 0x7F);
    vals[8]  = (float)((cpack >> 35) & 0x7F);
    vals[9]  = (float)((cpack >> 42) & 0x7F);
    vals[10] = (float)((cpack >> 49) & 0x7F);
    vals[11] = (float)((cpack >> 56) & 0x7F);
    vals[12] = (float)dsum_p; vals[13] = (float)dcnt_p;
    vals[14] = (float)dsum_g; vals[15] = (float)dcnt_g;
    #pragma unroll
    for (int j = 0; j < 16; ++j)
        #pragma unroll
        for (int off = 32; off; off >>= 1)
            vals[j] += __shfl_down(vals[j], off, 64);
    if (lane == 0) {
        #pragma unroll
        for (int j = 0; j < 16; ++j) red[wid][j] = vals[j];
    }
    __syncthreads();
    if (tid < 16) {
        float s = 0.f;
        #pragma unroll
        for (int wv = 0; wv < NW; ++wv) s += red[wv][tid];
        part[fid * NACC + tid] = s;
    }
}

// ---------------------------------------------------------------------------
// Final: reduce 512x16 partials -> 32x16 -> scalar. One block, deterministic.
// ---------------------------------------------------------------------------
__global__ __launch_bounds__(512) void final_kernel(
    const float* __restrict__ part, float* __restrict__ out)
{
    __shared__ float sacc[BATCH][NACC];
    __shared__ float tri[BATCH][3];
    int t = threadIdx.x;
    {
        int b = t >> 4, k = t & 15;
        float s = 0.f;
        #pragma unroll 4
        for (int j = 0; j < NTILE; ++j)            // fid = j*32 + b
            s += part[((j << 5) + b) * NACC + k];
        sacc[b][k] = s;
    }
    __syncthreads();
    if (t < BATCH) {
        const float* a = sacc[t];
        float inter = a[0], psum = a[1], gsum = a[2];
        float dice = (2.f * inter + 1.f) / (psum + gsum + 1.f);

        float pe = a[3], pm = a[4], pj = a[5];
        float ge = a[6], gm = a[7], gj = a[8];
        float ie = a[9], im = a[10], ij = a[11];
        float e_iou = (ie + 1.f) / (pe + ge - ie + 1.f);
        float m_iou = (im + 1.f) / (pm + gm - im + 1.f);
        float j_iou = (ij + 1.f) / (pj + gj - ij + 1.f);
        float total = ge + gj + gm + 1.f;
        float sloss = 1.f - ((ge / total) * e_iou + (gj / total) * j_iou + (gm / total) * m_iou);

        float p2g = a[12] / (a[13] + 1.f);
        float g2p = a[14] / (a[15] + 1.f);
        float med = ((p2g + g2p) * 0.5f) / 10.f;
        tri[t][0] = dice; tri[t][1] = sloss; tri[t][2] = med;
    }
    __syncthreads();
    if (t == 0) {
        float dice = 0.f, sloss = 0.f, med = 0.f;
        for (int b = 0; b < BATCH; ++b) {
            dice += tri[b][0]; sloss += tri[b][1]; med += tri[b][2];
        }
        float dice_loss  = 1.f - dice / (float)BATCH;
        float structural = sloss / (float)BATCH;
        float medial     = med / (float)BATCH;
        float avg = (dice_loss + structural + medial) / 3.f;
        float r = dice_loss  / (dice_loss  + 1.f) * avg
                + structural / (structural + 1.f) * avg
                + medial     / (medial     + 1.f) * avg;
        out[0] = r;
    }
}

extern "C" void kernel_launch(void* const* d_in, const int* in_sizes, int n_in,
                              void* d_out, int out_size, void* d_ws, size_t ws_size,
                              hipStream_t stream)
{
    const float* pred = (const float*)d_in[0];
    const float* gt   = (const float*)d_in[1];
    float* part = (float*)d_ws;
    float* out  = (float*)d_out;

    fused_kernel<<<dim3(NBLK), NT, 0, stream>>>(pred, gt, part);
    final_kernel<<<1, 512, 0, stream>>>(part, out);
}